// Round 14
// baseline (1497.523 us; speedup 1.0000x reference)
//
#include <hip/hip_runtime.h>

namespace {

constexpr int NX = 384, NY = 384, NZ = 48;
constexpr int NXU = NX + 1;
constexpr int PLN = NX * NY;
constexpr float RDX = 1.0f / 1000.0f;
constexpr float RDY = 1.0f / 1000.0f;
constexpr float RDZ = 49.0f;              // 1/DZ
constexpr float PREF = 100000.0f, G = 9.81f;
constexpr float K_RP = 287.0f / PREF;

constexpr int SZ_U = NZ * NY * NXU;
constexpr int SZ_V = NZ * (NY + 1) * NX;
constexpr int SZ_W = (NZ - 1) * PLN;
constexpr int SZ_T = NZ * PLN;
constexpr int SZ_M = NZ * PLN;
constexpr int SZ_P = (NZ - 1) * PLN;

// tile geometry (32x8)
constexpr int TX = 32, TY = 8;            // 256 threads
constexpr int PW = TX + 3;                // 35
constexpr int PH = TY + 3;                // 11
constexpr int PSZ = PW * PH;              // 385
constexpr int WW = PW + 1;                // 36 wide-mu plane
constexpr int WH = PH + 1;                // 12
constexpr int WSZ = WW * WH;              // 432
constexpr int KCH = 12, KSPLIT = 4;

// grid / swizzle
constexpr int GX = NX / TX;               // 12
constexpr int GY = NY / TY;               // 48
constexpr int NWG = GX * GY * KSPLIT;     // 2304 (div by 8)
constexpr int CPX = NWG / 8;              // 288

// LDS float offsets (9,043 floats = 36,172 B -> 4 blocks/CU)
constexpr int O_PH = 0;                   // 5 x 385 : PHIP(m+1) at slot m%5
constexpr int O_MS = O_PH + 5 * PSZ;      // 4 x 432 : Ms wide, slot l%4
constexpr int O_P  = O_MS + 4 * WSZ;      // 3 x 385 : p-pad(l+1), slot l%3
constexpr int O_OM = O_P  + 3 * PSZ;      // 3 x 385 : Omega, slot l%3
constexpr int O_TH = O_OM + 3 * PSZ;      // 2 x 385
constexpr int O_u  = O_TH + 2 * PSZ;      // 2 x 385
constexpr int O_v  = O_u  + 2 * PSZ;      // 2 x 385
constexpr int O_w  = O_v  + 2 * PSZ;      // 2 x 385
constexpr int LTOT = O_w + 2 * PSZ;       // 9,043

struct PIdx { int pix, uo, vo, wc, oxa, oxb, oya, oyb; };

__device__ __forceinline__ float frcp(float x) { return __builtin_amdgcn_rcpf(x); }
__device__ __forceinline__ float pow14(float x) {
    return __builtin_amdgcn_exp2f(1.4f * __builtin_amdgcn_logf(x));
}
__device__ __forceinline__ void gll4(const float* src, float* ldsWaveBase) {
    __builtin_amdgcn_global_load_lds(
        (const __attribute__((address_space(1))) void*)src,
        (__attribute__((address_space(3))) void*)ldsWaveBase, 4, 0, 0);
}
__device__ __forceinline__ int imin(int a, int b) { return a < b ? a : b; }
__device__ __forceinline__ int imax(int a, int b) { return a > b ? a : b; }

__global__ __launch_bounds__(256, 4)
void rhs_tile(
    const float* __restrict__ Us, const float* __restrict__ Vs, const float* __restrict__ Ws,
    const float* __restrict__ Ts, const float* __restrict__ Ms, const float* __restrict__ Ps,
    const float* __restrict__ Phit, const float* __restrict__ Phis,
    const float* __restrict__ Pt,   const float* __restrict__ Psrf,
    const float* __restrict__ U0, const float* __restrict__ V0, const float* __restrict__ W0,
    const float* __restrict__ T0, const float* __restrict__ M0, const float* __restrict__ P0,
    float* __restrict__ Uo, float* __restrict__ Vo, float* __restrict__ Wo,
    float* __restrict__ To, float* __restrict__ Mo, float* __restrict__ Po,
    const int* __restrict__ dtp, float coef)
{
    __shared__ float L[LTOT];

    const int tx = threadIdx.x, ty = threadIdx.y;
    const int tid = ty * TX + tx;

    // XCD-aware bijective block swizzle
    const int flat = blockIdx.x + GX * (blockIdx.y + GY * blockIdx.z);
    const int nf   = (flat & 7) * CPX + (flat >> 3);
    const int bx   = nf % GX;
    const int by   = (nf / GX) % GY;
    const int bz   = nf / (GX * GY);
    const int i0 = bx * TX;
    const int j0 = by * TY;
    const int k0 = bz * KCH;

    const int i = i0 + tx, j = j0 + ty;
    const float c = coef * (float)(*dtp);
    const int ly = ty + 1, lx = tx + 1;
    const int wb = tid & ~63;               // wave-uniform LDS base
    const bool hasB = (tid + 256 < PSZ);    // B plane point exists (tid < 129)
    const bool hasW = (tid + 256 < WSZ);    // B wide point (tid < 176)

    // ---- per-point index sets (seam-corrected wide-mu pairs) ----
    auto mkpt = [&](int idx, PIdx& q) {
        const int r = idx / PW, cc = idx - r * PW;
        int gj = j0 - 1 + r;  if (gj < 0) gj += NY; else if (gj >= NY) gj -= NY;
        int gi = i0 - 1 + cc; if (gi < 0) gi += NX; else if (gi >= NX) gi -= NX;
        int gII = i0 - 1 + cc; if (gII < 0) gII += NX + 1; else if (gII > NX) gII -= NX + 1;
        int gJJ = j0 - 1 + r;  if (gJJ < 0) gJJ += NY + 1; else if (gJJ > NY) gJJ -= NY + 1;
        q.pix = gj * NX + gi;
        q.uo  = gj * NXU + gII;
        q.vo  = gJJ * NX + gi;
        q.wc  = (r + 1) * WW + (cc + 1);
        q.oxa = q.wc - 1; q.oxb = q.wc;
        if (i0 == 0 && cc == 0) { q.oxa = q.wc; q.oxb = q.wc + 1; }
        q.oya = q.wc - WW; q.oyb = q.wc;
        if (j0 == 0 && r == 0)  { q.oya = q.wc; q.oyb = q.wc + WW; }
    };
    auto mkwide = [&](int idxw) -> int {
        const int r = idxw / WW, cc = idxw - r * WW;
        int gj = j0 - 2 + r;  if (gj < 0) gj += NY; else if (gj >= NY) gj -= NY;
        int gi = i0 - 2 + cc; if (gi < 0) gi += NX; else if (gi >= NX) gi -= NX;
        return gj * NX + gi;
    };
    PIdx A, B;
    mkpt(tid, A);
    mkpt(imin(tid + 256, PSZ - 1), B);
    const int pwA = mkwide(tid);
    const int pwB = mkwide(imin(tid + 256, WSZ - 1));

    // tails
    const int msT = tid - 128;                         // MS tail entries 384..431
    const bool hasMsT = (msT >= 0 && msT < WSZ - 384); // threads 128..175
    const int pwT = mkwide(hasMsT ? (384 + msT) : 0);
    int p384;                                          // PH tail entry 384 pix
    { PIdx tq; mkpt(PSZ - 1, tq); p384 = tq.pix; }
    const bool hasPhT = (tid == 176);

    // ---- async stage for iteration k: PH[k+3], MS[k+3] (wave-uniform gll) ----
    auto stage = [&](int k) {
        const int m = k + 3;
        const float* sA = (m >= NZ - 1) ? &Phis[A.pix] : &Ps[m * PLN + A.pix];
        gll4(sA, &L[O_PH + (m % 5) * PSZ + wb]);
        if (tid < 128) {
            const float* sB = (m >= NZ - 1) ? &Phis[B.pix] : &Ps[m * PLN + B.pix];
            gll4(sB, &L[O_PH + (m % 5) * PSZ + wb + 256]);
        }
        const int lm = imin(m, NZ - 1);
        gll4(&Ms[lm * PLN + pwA], &L[O_MS + (m % 4) * WSZ + wb]);
        if (tid < 128) gll4(&Ms[lm * PLN + pwB], &L[O_MS + (m % 4) * WSZ + wb + 256]);
    };
    auto stage_tail = [&](int k) {      // plain writes into (k+3) slots; compute phase
        const int m = k + 3;
        if (hasPhT) {
            L[O_PH + (m % 5) * PSZ + (PSZ - 1)] =
                (m >= NZ - 1) ? Phis[p384] : Ps[m * PLN + p384];
        }
        if (hasMsT) {
            const int lm = imin(m, NZ - 1);
            L[O_MS + (m % 4) * WSZ + 384 + msT] = Ms[lm * PLN + pwT];
        }
    };

    // ---- derive level l for one point (raw U,V,Ts,Ws come from registers) ----
    auto derive = [&](int l, int idx, const PIdx& q, float Uv, float Vv, float tsv, float wsv) {
        const int s3 = ((l % 3) + 3) % 3, s2 = l & 1;
        float pv, th = 0.f, uv = 0.f, vv = 0.f, wv = 0.f, om = 0.f;
        if (l >= 0 && l < NZ) {
            const int m4 = l % 4, m5 = l % 5, p5 = ((l - 1) % 5 + 5) % 5;
            const float mu  = L[O_MS + m4 * WSZ + q.wc];
            const float phv = L[O_PH + m5 * PSZ + idx];
            const float phm = L[O_PH + p5 * PSZ + idx];
            const float rmu = frcp(mu);
            const float al  = -(phv - phm) * RDZ * rmu;
            th = tsv * rmu;
            pv = PREF * pow14(K_RP * th * frcp(al));
            uv = Uv * frcp(0.5f * (L[O_MS + m4 * WSZ + q.oxa] + L[O_MS + m4 * WSZ + q.oxb]));
            vv = Vv * frcp(0.5f * (L[O_MS + m4 * WSZ + q.oya] + L[O_MS + m4 * WSZ + q.oyb]));
            if (l < NZ - 1) {
                const float mu1 = L[O_MS + ((l + 1) % 4) * WSZ + q.wc];
                const float ph1 = L[O_PH + ((l + 1) % 5) * PSZ + idx];
                const float al1 = -(ph1 - phv) * RDZ * frcp(mu1);
                const float mz  = 0.5f * (mu + mu1);
                wv = wsv * frcp(mz);
                om = -wsv * G * frcp(0.5f * (al + al1) * mz);
            }
        } else {
            pv = (l < 0) ? Pt[q.pix] : Psrf[q.pix];
        }
        L[O_P  + s3 * PSZ + idx] = pv;
        L[O_OM + s3 * PSZ + idx] = om;
        L[O_TH + s2 * PSZ + idx] = th;
        L[O_u  + s2 * PSZ + idx] = uv;
        L[O_v  + s2 * PSZ + idx] = vv;
        L[O_w  + s2 * PSZ + idx] = wv;
    };

    // ================= prologue: plain ring fills =================
    {
        for (int m = k0 - 2; m <= k0 + 2; ++m) {
            const float v = (m >= NZ - 1) ? Phis[A.pix]
                          : ((m < 0) ? Phit[A.pix] : Ps[m * PLN + A.pix]);
            L[O_PH + ((m % 5 + 5) % 5) * PSZ + tid] = v;
        }
        for (int l = k0 - 1; l <= k0 + 2; ++l) {
            const int lc = imin(imax(l, 0), NZ - 1);
            L[O_MS + ((l % 4 + 4) % 4) * WSZ + tid] = Ms[lc * PLN + pwA];
        }
        if (hasB) {
            const int idx = tid + 256;
            for (int m = k0 - 2; m <= k0 + 2; ++m) {
                const float v = (m >= NZ - 1) ? Phis[B.pix]
                              : ((m < 0) ? Phit[B.pix] : Ps[m * PLN + B.pix]);
                L[O_PH + ((m % 5 + 5) % 5) * PSZ + idx] = v;
            }
        }
        if (hasW) {
            const int idx = tid + 256;
            for (int l = k0 - 1; l <= k0 + 2; ++l) {
                const int lc = imin(imax(l, 0), NZ - 1);
                L[O_MS + ((l % 4 + 4) % 4) * WSZ + idx] = Ms[lc * PLN + pwB];
            }
        }
    }
    __syncthreads();

    {   // prologue derives (raw fields straight from global)
        int lc = imin(imax(k0 - 1, 0), NZ - 1), lw = imin(imax(k0 - 1, 0), NZ - 2);
        derive(k0 - 1, tid, A, Us[lc * NY * NXU + A.uo], Vs[lc * (NY + 1) * NX + A.vo],
               Ts[lc * PLN + A.pix], Ws[lw * PLN + A.pix]);
        if (hasB) derive(k0 - 1, tid + 256, B, Us[lc * NY * NXU + B.uo],
                         Vs[lc * (NY + 1) * NX + B.vo], Ts[lc * PLN + B.pix], Ws[lw * PLN + B.pix]);
        lc = imin(k0, NZ - 1); lw = imin(k0, NZ - 2);
        derive(k0, tid, A, Us[lc * NY * NXU + A.uo], Vs[lc * (NY + 1) * NX + A.vo],
               Ts[lc * PLN + A.pix], Ws[lw * PLN + A.pix]);
        if (hasB) derive(k0, tid + 256, B, Us[lc * NY * NXU + B.uo],
                         Vs[lc * (NY + 1) * NX + B.vo], Ts[lc * PLN + B.pix], Ws[lw * PLN + B.pix]);
    }

    // stage raw-field registers for level k0+1
    float cUa, cVa, cTa, cWa, cUb = 0.f, cVb = 0.f, cTb = 0.f, cWb = 0.f;
    {
        const int lc = imin(k0 + 1, NZ - 1), lw = imin(k0 + 1, NZ - 2);
        cUa = Us[lc * NY * NXU + A.uo]; cVa = Vs[lc * (NY + 1) * NX + A.vo];
        cTa = Ts[lc * PLN + A.pix];     cWa = Ws[lw * PLN + A.pix];
        if (hasB) {
            cUb = Us[lc * NY * NXU + B.uo]; cVb = Vs[lc * (NY + 1) * NX + B.vo];
            cTb = Ts[lc * PLN + B.pix];     cWb = Ws[lw * PLN + B.pix];
        }
    }
    __syncthreads();

    // carried k-1 center registers
    const int e0 = (k0 - 1) & 1;
    float th_m  = L[O_TH + e0 * PSZ + ly * PW + lx];
    float u_m   = L[O_u  + e0 * PSZ + ly * PW + lx];
    float u_m_e = L[O_u  + e0 * PSZ + ly * PW + lx + 1];
    float v_m   = L[O_v  + e0 * PSZ + ly * PW + lx];
    float v_m_e = L[O_v  + e0 * PSZ + (ly + 1) * PW + lx];
    float w_m   = L[O_w  + e0 * PSZ + ly * PW + lx];

    // ================= main k loop =================
    for (int k = k0; k < k0 + KCH; ++k) {
        derive(k + 1, tid, A, cUa, cVa, cTa, cWa);
        if (hasB) derive(k + 1, tid + 256, B, cUb, cVb, cTb, cWb);
        __syncthreads();

        if (k < k0 + KCH - 1) {
            stage(k);
            stage_tail(k);
            const int lc = imin(k + 2, NZ - 1), lw = imin(k + 2, NZ - 2);
            cUa = Us[lc * NY * NXU + A.uo]; cVa = Vs[lc * (NY + 1) * NX + A.vo];
            cTa = Ts[lc * PLN + A.pix];     cWa = Ws[lw * PLN + A.pix];
            if (hasB) {
                cUb = Us[lc * NY * NXU + B.uo]; cVb = Vs[lc * (NY + 1) * NX + B.vo];
                cTb = Ts[lc * PLN + B.pix];     cWb = Ws[lw * PLN + B.pix];
            }
        }

        const int a5 = (k + 4) % 5, b5 = k % 5, c5 = (k + 1) % 5;
        const int aP = (k + 2) % 3, bP = k % 3, cP = (k + 1) % 3;
        const int m4 = k % 4, n4 = (k + 1) % 4;
        const int e = k & 1, f = 1 - e;

        auto PHx = [&](int s, int rr, int cc) { return L[O_PH + s * PSZ + rr * PW + cc]; };
        auto Px  = [&](int s, int rr, int cc) { return L[O_P  + s * PSZ + rr * PW + cc]; };
        auto Ox  = [&](int s, int rr, int cc) { return L[O_OM + s * PSZ + rr * PW + cc]; };
        auto MSW = [&](int s, int widx)       { return L[O_MS + s * WSZ + widx]; };
        auto MUx = [&](int s, int rr, int cc) { return MSW(s, (rr + 1) * WW + cc + 1); };
        auto THx = [&](int s, int rr, int cc) { return L[O_TH + s * PSZ + rr * PW + cc]; };
        auto ux  = [&](int s, int rr, int cc) { return L[O_u  + s * PSZ + rr * PW + cc]; };
        auto vx  = [&](int s, int rr, int cc) { return L[O_v  + s * PSZ + rr * PW + cc]; };
        auto wx  = [&](int s, int rr, int cc) { return L[O_w  + s * PSZ + rr * PW + cc]; };
        auto MUXP = [&](int s, int rr, int cc) {      // x-staggered mu pair (seam-aware)
            const int wc = (rr + 1) * WW + cc + 1;
            const bool sm = (i0 == 0) && (cc == 0);
            return 0.5f * (MSW(s, sm ? wc : wc - 1) + MSW(s, sm ? wc + 1 : wc));
        };
        auto MUYP = [&](int s, int rr, int cc) {      // y-staggered mu pair (seam-aware)
            const int wc = (rr + 1) * WW + cc + 1;
            const bool sm = (j0 == 0) && (rr == 0);
            return 0.5f * (MSW(s, sm ? wc : wc - WW) + MSW(s, sm ? wc + WW : wc));
        };
        auto Ur = [&](int s2, int s4, int rr, int cc) { return ux(s2, rr, cc) * MUXP(s4, rr, cc); };
        auto Vr = [&](int s2, int s4, int rr, int cc) { return vx(s2, rr, cc) * MUYP(s4, rr, cc); };
        auto ALk = [&](int rr, int cc) {
            return -(PHx(b5, rr, cc) - PHx(a5, rr, cc)) * RDZ * frcp(MUx(m4, rr, cc));
        };

        // ---- R_U at staggered col cc ----
        auto R_U_c = [&](int cc, float ukm) -> float {
            const float u0 = ux(e, ly, cc), um = ux(e, ly, cc - 1), up = ux(e, ly, cc + 1);
            const float Uc = Ur(e, m4, ly, cc), Um = Ur(e, m4, ly, cc - 1), Up = Ur(e, m4, ly, cc + 1);
            float r = -0.25f * ((Uc + Up) * (u0 + up) - (Um + Uc) * (um + u0)) * RDX;
            const float VBj  = 0.5f * (Vr(e, m4, ly, cc - 1) + Vr(e, m4, ly, cc));
            const float VBj1 = 0.5f * (Vr(e, m4, ly + 1, cc - 1) + Vr(e, m4, ly + 1, cc));
            const float uS = ux(e, ly - 1, cc), uN = ux(e, ly + 1, cc);
            r -= (VBj1 * 0.5f * (u0 + uN) - VBj * 0.5f * (uS + u0)) * RDY;
            const float OBk  = 0.5f * (Ox(aP, ly, cc - 1) + Ox(aP, ly, cc));
            const float OBk1 = 0.5f * (Ox(bP, ly, cc - 1) + Ox(bP, ly, cc));
            const float ukp = ux(f, ly, cc);
            r -= (OBk1 * 0.5f * (u0 + ukp) - OBk * 0.5f * (ukm + u0)) * RDZ;
            const float mux_ = MUXP(m4, ly, cc);
            const float alx  = 0.5f * (ALk(ly, cc - 1) + ALk(ly, cc));
            const float dpx  = (Px(bP, ly, cc) - Px(bP, ly, cc - 1)) * RDX;
            r -= mux_ * alx * dpx;
            const float pzk  = 0.25f * (Px(aP, ly, cc - 1) + Px(bP, ly, cc - 1)
                                      + Px(aP, ly, cc)     + Px(bP, ly, cc));
            const float pzk1 = 0.25f * (Px(bP, ly, cc - 1) + Px(cP, ly, cc - 1)
                                      + Px(bP, ly, cc)     + Px(cP, ly, cc));
            const float dpz = (pzk1 - pzk) * RDZ;
            const float pza = 0.5f * (PHx(a5, ly, cc - 1) + PHx(b5, ly, cc - 1));
            const float pzb = 0.5f * (PHx(a5, ly, cc)     + PHx(b5, ly, cc));
            r -= dpz * (pzb - pza) * RDX;
            return r;
        };

        // ---- R_V at staggered row rr ----
        auto R_V_c = [&](int rr, float vkm) -> float {
            const float v0 = vx(e, rr, lx), vm = vx(e, rr - 1, lx), vp = vx(e, rr + 1, lx);
            const float Vc = Vr(e, m4, rr, lx), Vm = Vr(e, m4, rr - 1, lx), Vp = Vr(e, m4, rr + 1, lx);
            float r = -0.25f * ((Vc + Vp) * (v0 + vp) - (Vm + Vc) * (vm + v0)) * RDY;
            const float UBi  = 0.5f * (Ur(e, m4, rr - 1, lx)     + Ur(e, m4, rr, lx));
            const float UBi1 = 0.5f * (Ur(e, m4, rr - 1, lx + 1) + Ur(e, m4, rr, lx + 1));
            const float vW = vx(e, rr, lx - 1), vE = vx(e, rr, lx + 1);
            r -= (UBi1 * 0.5f * (v0 + vE) - UBi * 0.5f * (vW + v0)) * RDX;
            const float OBk  = 0.5f * (Ox(aP, rr - 1, lx) + Ox(aP, rr, lx));
            const float OBk1 = 0.5f * (Ox(bP, rr - 1, lx) + Ox(bP, rr, lx));
            const float vkp = vx(f, rr, lx);
            r -= (OBk1 * 0.5f * (v0 + vkp) - OBk * 0.5f * (vkm + v0)) * RDZ;
            const float muy = MUYP(m4, rr, lx);
            const float aly = 0.5f * (ALk(rr - 1, lx) + ALk(rr, lx));
            const float dpy = (Px(bP, rr, lx) - Px(bP, rr - 1, lx)) * RDY;
            r -= muy * aly * dpy;
            const float pzk  = 0.25f * (Px(aP, rr - 1, lx) + Px(bP, rr - 1, lx)
                                      + Px(aP, rr, lx)     + Px(bP, rr, lx));
            const float pzk1 = 0.25f * (Px(bP, rr - 1, lx) + Px(cP, rr - 1, lx)
                                      + Px(bP, rr, lx)     + Px(cP, rr, lx));
            const float dpz = (pzk1 - pzk) * RDZ;
            const float pza = 0.5f * (PHx(a5, rr - 1, lx) + PHx(b5, rr - 1, lx));
            const float pzb = 0.5f * (PHx(a5, rr, lx)     + PHx(b5, rr, lx));
            r -= dpz * (pzb - pza) * RDY;
            return r;
        };

        // ===== R_Theta =====
        const float th0 = THx(e, ly, lx);
        float rT = -(Ur(e, m4, ly, lx + 1) * 0.5f * (th0 + THx(e, ly, lx + 1))
                   - Ur(e, m4, ly, lx)     * 0.5f * (THx(e, ly, lx - 1) + th0)) * RDX
                   -(Vr(e, m4, ly + 1, lx) * 0.5f * (th0 + THx(e, ly + 1, lx))
                   - Vr(e, m4, ly, lx)     * 0.5f * (THx(e, ly - 1, lx) + th0)) * RDY;
        const float th_p = THx(f, ly, lx);
        const float Hk  = Ox(aP, ly, lx) * 0.5f * (th_m + th0);
        const float Hk1 = Ox(bP, ly, lx) * 0.5f * (th0 + th_p);
        rT -= (Hk1 - Hk) * RDZ;

        // ===== R_Mu =====
        const float rM = -(Ur(e, m4, ly, lx + 1) - Ur(e, m4, ly, lx)) * RDX
                         -(Vr(e, m4, ly + 1, lx) - Vr(e, m4, ly, lx)) * RDY
                         -(Ox(bP, ly, lx) - Ox(aP, ly, lx)) * RDZ;

        // ===== stores (center) =====
        const int idc = (k * NY + j) * NX + i;
        To[idc] = T0[idc] + c * rT;
        Mo[idc] = M0[idc] + c * rM;
        const int idu = (k * NY + j) * NXU + i;
        Uo[idu] = U0[idu] + c * R_U_c(lx, u_m);
        const int idv = (k * (NY + 1) + j) * NX + i;
        Vo[idv] = V0[idv] + c * R_V_c(ly, v_m);

        // ===== R_W / R_Phi at half level k =====
        if (k < NZ - 1) {
            const float w0 = wx(e, ly, lx);
            const float Uzi  = 0.5f * (Ur(e, m4, ly, lx)     + Ur(f, n4, ly, lx));
            const float Uzi1 = 0.5f * (Ur(e, m4, ly, lx + 1) + Ur(f, n4, ly, lx + 1));
            const float wW = wx(e, ly, lx - 1), wE = wx(e, ly, lx + 1);
            float rW = -(Uzi1 * 0.5f * (w0 + wE) - Uzi * 0.5f * (wW + w0)) * RDX;
            const float Vzj  = 0.5f * (Vr(e, m4, ly, lx)     + Vr(f, n4, ly, lx));
            const float Vzj1 = 0.5f * (Vr(e, m4, ly + 1, lx) + Vr(f, n4, ly + 1, lx));
            const float wS = wx(e, ly - 1, lx), wN = wx(e, ly + 1, lx);
            rW -= (Vzj1 * 0.5f * (w0 + wN) - Vzj * 0.5f * (wS + w0)) * RDY;
            const float OZk  = 0.5f * (Ox(aP, ly, lx) + Ox(bP, ly, lx));
            const float OZk1 = 0.5f * (Ox(bP, ly, lx) + Ox(cP, ly, lx));
            const float wkp = wx(f, ly, lx);
            rW -= (OZk1 * 0.5f * (w0 + wkp) - OZk * 0.5f * (w_m + w0)) * RDZ;
            const float muz = 0.5f * (MUx(m4, ly, lx) + MUx(n4, ly, lx));
            rW += G * ((Px(cP, ly, lx) - Px(bP, ly, lx)) * RDZ - muz);

            const float ubz = 0.25f * (ux(e, ly, lx) + ux(e, ly, lx + 1)
                                     + ux(f, ly, lx) + ux(f, ly, lx + 1));
            const float dfx = (PHx(b5, ly, lx + 1) - PHx(b5, ly, lx - 1)) * (0.5f * RDX);
            const float vbz = 0.25f * (vx(e, ly, lx) + vx(e, ly + 1, lx)
                                     + vx(f, ly, lx) + vx(f, ly + 1, lx));
            const float dfy = (PHx(b5, ly + 1, lx) - PHx(b5, ly - 1, lx)) * (0.5f * RDY);
            const float rmuz = frcp(muz);
            const float om   = Ox(bP, ly, lx) * rmuz;
            const float dfz  = (PHx(c5, ly, lx) - PHx(a5, ly, lx)) * (0.5f * RDZ);
            const float rP = -ubz * dfx - vbz * dfy - om * dfz + G * w0;

            Wo[idc] = W0[idc] + c * rW;
            Po[idc] = P0[idc] + c * rP;
        }

        // ===== extra staggered col II=NX / row JJ=NY =====
        if (i == NX - 1) {
            Uo[idu + 1] = U0[idu + 1] + c * R_U_c(lx + 1, u_m_e);
        }
        if (j == NY - 1) {
            const int idv2 = (k * (NY + 1) + NY) * NX + i;
            Vo[idv2] = V0[idv2] + c * R_V_c(ly + 1, v_m_e);
        }

        // ===== capture k-1 carries =====
        th_m  = th0;
        u_m   = ux(e, ly, lx);
        u_m_e = ux(e, ly, lx + 1);
        v_m   = vx(e, ly, lx);
        v_m_e = vx(e, ly + 1, lx);
        w_m   = wx(e, ly, lx);

        __syncthreads();   // drains staged gll + reg loads; next derive may consume
    }
}

} // anonymous namespace

extern "C" void kernel_launch(void* const* d_in, const int* in_sizes, int n_in,
                              void* d_out, int out_size, void* d_ws, size_t ws_size,
                              hipStream_t stream)
{
    (void)in_sizes; (void)n_in; (void)out_size; (void)ws_size;

    const float* U0   = (const float*)d_in[0];
    const float* V0   = (const float*)d_in[1];
    const float* W0   = (const float*)d_in[2];
    const float* T0   = (const float*)d_in[3];
    const float* M0   = (const float*)d_in[4];
    const float* P0   = (const float*)d_in[5];
    const float* Phit = (const float*)d_in[6];
    const float* Phis = (const float*)d_in[7];
    const float* Pt   = (const float*)d_in[8];
    const float* Psrf = (const float*)d_in[9];
    const int*   dtp  = (const int*)d_in[10];

    float* out = (float*)d_out;
    float* ws  = (float*)d_ws;

    float* outU = out;
    float* outV = outU + SZ_U;
    float* outW = outV + SZ_V;
    float* outT = outW + SZ_W;
    float* outM = outT + SZ_T;
    float* outP = outM + SZ_M;

    float* wsU = ws;
    float* wsV = wsU + SZ_U;
    float* wsW = wsV + SZ_V;
    float* wsT = wsW + SZ_W;
    float* wsM = wsT + SZ_T;
    float* wsP = wsM + SZ_M;

    const dim3 blk(TX, TY, 1);
    const dim3 grd(GX, GY, KSPLIT);

    const float coefs[3] = {1.0f / 3.0f, 0.5f, 1.0f};

    // stage ping-pong: d_in -> d_out -> ws -> d_out
    const float* sU[3] = {U0, outU, wsU};
    const float* sV[3] = {V0, outV, wsV};
    const float* sW[3] = {W0, outW, wsW};
    const float* sT[3] = {T0, outT, wsT};
    const float* sM[3] = {M0, outM, wsM};
    const float* sP_[3] = {P0, outP, wsP};
    float* oU[3] = {outU, wsU, outU};
    float* oV[3] = {outV, wsV, outV};
    float* oW[3] = {outW, wsW, outW};
    float* oT[3] = {outT, wsT, outT};
    float* oM[3] = {outM, wsM, outM};
    float* oP[3] = {outP, wsP, outP};

    for (int s = 0; s < 3; ++s) {
        rhs_tile<<<grd, blk, 0, stream>>>(
            sU[s], sV[s], sW[s], sT[s], sM[s], sP_[s],
            Phit, Phis, Pt, Psrf,
            U0, V0, W0, T0, M0, P0,
            oU[s], oV[s], oW[s], oT[s], oM[s], oP[s],
            dtp, coefs[s]);
    }
}

// Round 15
// 539.041 us; speedup vs baseline: 2.7781x; 2.7781x over previous
//
#include <hip/hip_runtime.h>

namespace {

constexpr int NX = 384, NY = 384, NZ = 48;
constexpr int NXU = NX + 1;
constexpr int PLN = NX * NY;
constexpr float RDX = 1.0f / 1000.0f;
constexpr float RDY = 1.0f / 1000.0f;
constexpr float RDZ = 49.0f;              // 1/DZ, DZ = 1/(NZ+1)
constexpr float PREF = 100000.0f, G = 9.81f;
constexpr float K_RP = 287.0f / PREF;

constexpr int SZ_U = NZ * NY * NXU;
constexpr int SZ_V = NZ * (NY + 1) * NX;
constexpr int SZ_W = (NZ - 1) * PLN;
constexpr int SZ_T = NZ * PLN;
constexpr int SZ_M = NZ * PLN;
constexpr int SZ_P = (NZ - 1) * PLN;

// tile geometry (32x8: 2 rows/wave at stride 35 -> 2-way LDS banking = free)
constexpr int TX = 32, TY = 8;            // 256 threads
constexpr int PW = TX + 3;                // 35 (cols i0-1 .. i0+33, incl. stagger col)
constexpr int PH = TY + 3;                // 11
constexpr int PSZ = PW * PH;              // 385
constexpr int WW = PW + 1;                // 36 wide-Ms plane (extra left col/top row)
constexpr int WH = PH + 1;                // 12
constexpr int WSZ = WW * WH;              // 432
constexpr int ZP = 448;                   // padded gll plane (multiple of 64)
constexpr int KCH = 12, KSPLIT = 4;

// grid / swizzle constants
constexpr int GX = NX / TX;               // 12
constexpr int GY = NY / TY;               // 48
constexpr int NWG = GX * GY * KSPLIT;     // 2304 (divisible by 8)
constexpr int CPX = NWG / 8;              // 288 blocks per XCD chunk

// LDS float offsets
constexpr int O_PH = 0;                   // 5 x ZP  direct: PHIP(m+1) at slot m%5
constexpr int O_MS = O_PH + 5 * ZP;       // 4 x ZP  direct: Ms wide, slot l%4
constexpr int O_UR = O_MS + 4 * ZP;       // 3 x ZP  direct: Us, slot l%3
constexpr int O_VR = O_UR + 3 * ZP;       // 3 x ZP  direct: Vs, slot l%3
constexpr int O_TS = O_VR + 3 * ZP;       // 1 x ZP  zone: Ts
constexpr int O_WS = O_TS + ZP;           // 1 x ZP  zone: Ws
constexpr int O_P  = O_WS + ZP;           // 3 x PSZ derived p-pad(l+1) at slot l%3
constexpr int O_OM = O_P  + 3 * PSZ;      // 3 x PSZ derived Omega(half l) at slot l%3
constexpr int O_TH = O_OM + 3 * PSZ;      // 2 x PSZ
constexpr int O_u  = O_TH + 2 * PSZ;      // 2 x PSZ
constexpr int O_v  = O_u  + 2 * PSZ;      // 2 x PSZ
constexpr int O_w  = O_v  + 2 * PSZ;      // 2 x PSZ
constexpr int LTOT = O_w + 2 * PSZ;       // 13,006 floats = 52,024 B -> 3 blocks/CU

struct PIdx { int pix, uo, vo, wc, oxa, oxb, oya, oyb; };

__device__ __forceinline__ float frcp(float x) { return __builtin_amdgcn_rcpf(x); }
__device__ __forceinline__ float pow14(float x) {
    return __builtin_amdgcn_exp2f(1.4f * __builtin_amdgcn_logf(x));
}
__device__ __forceinline__ void gll4(const float* src, float* ldsWaveBase) {
    __builtin_amdgcn_global_load_lds(
        (const __attribute__((address_space(1))) void*)src,
        (__attribute__((address_space(3))) void*)ldsWaveBase, 4, 0, 0);
}
__device__ __forceinline__ int imin(int a, int b) { return a < b ? a : b; }
__device__ __forceinline__ int imax(int a, int b) { return a > b ? a : b; }

__global__ __launch_bounds__(256, 3)
void rhs_tile(
    const float* __restrict__ Us, const float* __restrict__ Vs, const float* __restrict__ Ws,
    const float* __restrict__ Ts, const float* __restrict__ Ms, const float* __restrict__ Ps,
    const float* __restrict__ Phit, const float* __restrict__ Phis,
    const float* __restrict__ Pt,   const float* __restrict__ Psrf,
    const float* __restrict__ U0, const float* __restrict__ V0, const float* __restrict__ W0,
    const float* __restrict__ T0, const float* __restrict__ M0, const float* __restrict__ P0,
    float* __restrict__ Uo, float* __restrict__ Vo, float* __restrict__ Wo,
    float* __restrict__ To, float* __restrict__ Mo, float* __restrict__ Po,
    const int* __restrict__ dtp, float coef)
{
    __shared__ float L[LTOT];

    const int tx = threadIdx.x, ty = threadIdx.y;
    const int tid = ty * TX + tx;

    // ---- XCD-aware bijective block swizzle (each XCD gets a contiguous chunk) ----
    const int flat = blockIdx.x + GX * (blockIdx.y + GY * blockIdx.z);
    const int nf   = (flat & 7) * CPX + (flat >> 3);
    const int bx   = nf % GX;
    const int by   = (nf / GX) % GY;
    const int bz   = nf / (GX * GY);
    const int i0 = bx * TX;
    const int j0 = by * TY;
    const int k0 = bz * KCH;

    const int i = i0 + tx, j = j0 + ty;
    const float c = coef * (float)(*dtp);
    const int ly = ty + 1, lx = tx + 1;
    const int wb = tid & ~63;               // wave-uniform LDS base offset
    const bool w2 = (tid < 192);            // wave-uniform: waves 0..2 stage B-span
    const bool hasB = (tid + 256 < PSZ);    // B plane point exists
    const bool hasW = (tid + 256 < WSZ);

    // ---- per-point index sets (seam-corrected wide-mu offsets) ----
    auto mkpt = [&](int idx, PIdx& q) {
        const int r = idx / PW, cc = idx - r * PW;
        int gj = j0 - 1 + r;  if (gj < 0) gj += NY; else if (gj >= NY) gj -= NY;
        int gi = i0 - 1 + cc; if (gi < 0) gi += NX; else if (gi >= NX) gi -= NX;
        int gII = i0 - 1 + cc; if (gII < 0) gII += NX + 1; else if (gII > NX) gII -= NX + 1;
        int gJJ = j0 - 1 + r;  if (gJJ < 0) gJJ += NY + 1; else if (gJJ > NY) gJJ -= NY + 1;
        q.pix = gj * NX + gi;
        q.uo  = gj * NXU + gII;
        q.vo  = gJJ * NX + gi;
        q.wc  = (r + 1) * WW + (cc + 1);
        q.oxa = q.wc - 1; q.oxb = q.wc;
        if (i0 == 0 && cc == 0) { q.oxa = q.wc; q.oxb = q.wc + 1; }   // gII==NX via left wrap
        q.oya = q.wc - WW; q.oyb = q.wc;
        if (j0 == 0 && r == 0)  { q.oya = q.wc; q.oyb = q.wc + WW; }  // gJJ==NY via top wrap
    };
    auto mkwide = [&](int idxw) -> int {
        const int r = idxw / WW, cc = idxw - r * WW;
        int gj = j0 - 2 + r;  if (gj < 0) gj += NY; else if (gj >= NY) gj -= NY;
        int gi = i0 - 2 + cc; if (gi < 0) gi += NX; else if (gi >= NX) gi -= NX;
        return gj * NX + gi;
    };
    PIdx A, B;
    mkpt(tid, A);
    mkpt(imin(tid + 256, PSZ - 1), B);
    const int pwA = mkwide(tid);
    const int pwB = mkwide(imin(tid + 256, WSZ - 1));

    // ---- async stage for iteration k: Φ[k+4], Ms[k+3], U/V/Ts/Ws[k+2] ----
    auto stage = [&](int k) {
        {   // PHIP(m+1), m = k+3 -> slot (k+3)%5
            const int m = k + 3;
            const float* sA = (m >= NZ - 1) ? &Phis[A.pix] : &Ps[m * PLN + A.pix];
            gll4(sA, &L[O_PH + (m % 5) * ZP + wb]);
            if (w2) {
                const float* sB = (m >= NZ - 1) ? &Phis[B.pix] : &Ps[m * PLN + B.pix];
                gll4(sB, &L[O_PH + (m % 5) * ZP + wb + 256]);
            }
        }
        {   // Ms wide, level k+3
            const int lm = imin(k + 3, NZ - 1);
            gll4(&Ms[lm * PLN + pwA], &L[O_MS + ((k + 3) % 4) * ZP + wb]);
            if (w2) gll4(&Ms[lm * PLN + pwB], &L[O_MS + ((k + 3) % 4) * ZP + wb + 256]);
        }
        {   // U, V, Ts level k+2 ; Ws level k+2 (clamped)
            const int lc = imin(k + 2, NZ - 1);
            gll4(&Us[lc * NY * NXU + A.uo], &L[O_UR + ((k + 2) % 3) * ZP + wb]);
            if (w2) gll4(&Us[lc * NY * NXU + B.uo], &L[O_UR + ((k + 2) % 3) * ZP + wb + 256]);
            gll4(&Vs[lc * (NY + 1) * NX + A.vo], &L[O_VR + ((k + 2) % 3) * ZP + wb]);
            if (w2) gll4(&Vs[lc * (NY + 1) * NX + B.vo], &L[O_VR + ((k + 2) % 3) * ZP + wb + 256]);
            gll4(&Ts[lc * PLN + A.pix], &L[O_TS + wb]);
            if (w2) gll4(&Ts[lc * PLN + B.pix], &L[O_TS + wb + 256]);
            const int lw = imin(k + 2, NZ - 2);
            gll4(&Ws[lw * PLN + A.pix], &L[O_WS + wb]);
            if (w2) gll4(&Ws[lw * PLN + B.pix], &L[O_WS + wb + 256]);
        }
    };

    // ---- derive level l into derived rings ----
    auto derive = [&](int l, int idx, const PIdx& q, float tsv, float wsv) {
        const int s3 = ((l % 3) + 3) % 3, s2 = l & 1;
        float pv, th = 0.f, uv = 0.f, vv = 0.f, wv = 0.f, om = 0.f;
        if (l >= 0 && l < NZ) {
            const int m4 = l % 4, m5 = l % 5, p5 = ((l - 1) % 5 + 5) % 5;
            const float mu  = L[O_MS + m4 * ZP + q.wc];
            const float phv = L[O_PH + m5 * ZP + idx];
            const float phm = L[O_PH + p5 * ZP + idx];
            const float rmu = frcp(mu);
            const float al  = -(phv - phm) * RDZ * rmu;
            th = tsv * rmu;
            pv = PREF * pow14(K_RP * th * frcp(al));
            uv = L[O_UR + (l % 3) * ZP + idx]
                 * frcp(0.5f * (L[O_MS + m4 * ZP + q.oxa] + L[O_MS + m4 * ZP + q.oxb]));
            vv = L[O_VR + (l % 3) * ZP + idx]
                 * frcp(0.5f * (L[O_MS + m4 * ZP + q.oya] + L[O_MS + m4 * ZP + q.oyb]));
            if (l < NZ - 1) {
                const float mu1 = L[O_MS + ((l + 1) % 4) * ZP + q.wc];
                const float ph1 = L[O_PH + ((l + 1) % 5) * ZP + idx];
                const float al1 = -(ph1 - phv) * RDZ * frcp(mu1);
                const float mz  = 0.5f * (mu + mu1);
                wv = wsv * frcp(mz);
                om = -wsv * G * frcp(0.5f * (al + al1) * mz);
            }
        } else {
            pv = (l < 0) ? Pt[q.pix] : Psrf[q.pix];
        }
        L[O_P  + s3 * PSZ + idx] = pv;
        L[O_OM + s3 * PSZ + idx] = om;
        L[O_TH + s2 * PSZ + idx] = th;
        L[O_u  + s2 * PSZ + idx] = uv;
        L[O_v  + s2 * PSZ + idx] = vv;
        L[O_w  + s2 * PSZ + idx] = wv;
    };

    // ================= prologue: direct ring fills =================
    {
        for (int m = k0 - 2; m <= k0 + 2; ++m) {
            const float v = (m >= NZ - 1) ? Phis[A.pix]
                          : ((m < 0) ? Phit[A.pix] : Ps[m * PLN + A.pix]);
            L[O_PH + ((m % 5 + 5) % 5) * ZP + tid] = v;
        }
        for (int l = k0 - 1; l <= k0 + 2; ++l) {
            const int lc = imin(imax(l, 0), NZ - 1);
            L[O_MS + ((l % 4 + 4) % 4) * ZP + tid] = Ms[lc * PLN + pwA];
        }
        for (int l = k0 - 1; l <= k0 + 1; ++l) {
            const int lc = imin(imax(l, 0), NZ - 1);
            L[O_UR + ((l % 3 + 3) % 3) * ZP + tid] = Us[lc * NY * NXU + A.uo];
            L[O_VR + ((l % 3 + 3) % 3) * ZP + tid] = Vs[lc * (NY + 1) * NX + A.vo];
        }
        if (hasB) {
            const int idx = tid + 256;
            for (int m = k0 - 2; m <= k0 + 2; ++m) {
                const float v = (m >= NZ - 1) ? Phis[B.pix]
                              : ((m < 0) ? Phit[B.pix] : Ps[m * PLN + B.pix]);
                L[O_PH + ((m % 5 + 5) % 5) * ZP + idx] = v;
            }
            for (int l = k0 - 1; l <= k0 + 1; ++l) {
                const int lc = imin(imax(l, 0), NZ - 1);
                L[O_UR + ((l % 3 + 3) % 3) * ZP + idx] = Us[lc * NY * NXU + B.uo];
                L[O_VR + ((l % 3 + 3) % 3) * ZP + idx] = Vs[lc * (NY + 1) * NX + B.vo];
            }
        }
        if (hasW) {
            const int idx = tid + 256;
            for (int l = k0 - 1; l <= k0 + 2; ++l) {
                const int lc = imin(imax(l, 0), NZ - 1);
                L[O_MS + ((l % 4 + 4) % 4) * ZP + idx] = Ms[lc * PLN + pwB];
            }
        }
    }
    __syncthreads();

    // prologue derives for levels k0-1, k0 (Ts/Ws direct from global)
    {
        int lc = imin(imax(k0 - 1, 0), NZ - 1), lw = imin(imax(k0 - 1, 0), NZ - 2);
        derive(k0 - 1, tid, A, Ts[lc * PLN + A.pix], Ws[lw * PLN + A.pix]);
        if (hasB) derive(k0 - 1, tid + 256, B, Ts[lc * PLN + B.pix], Ws[lw * PLN + B.pix]);
        lc = imin(k0, NZ - 1); lw = imin(k0, NZ - 2);
        derive(k0, tid, A, Ts[lc * PLN + A.pix], Ws[lw * PLN + A.pix]);
        if (hasB) derive(k0, tid + 256, B, Ts[lc * PLN + B.pix], Ws[lw * PLN + B.pix]);
    }
    {   // stage Ts/Ws zone for level k0+1
        const int lc = imin(k0 + 1, NZ - 1), lw = imin(k0 + 1, NZ - 2);
        gll4(&Ts[lc * PLN + A.pix], &L[O_TS + wb]);
        if (w2) gll4(&Ts[lc * PLN + B.pix], &L[O_TS + wb + 256]);
        gll4(&Ws[lw * PLN + A.pix], &L[O_WS + wb]);
        if (w2) gll4(&Ws[lw * PLN + B.pix], &L[O_WS + wb + 256]);
    }
    __syncthreads();   // drains gll; orders prologue derived-ring writes

    // carried k-1 center registers (level k0-1)
    const int e0 = (k0 - 1) & 1;
    float th_m  = L[O_TH + e0 * PSZ + ly * PW + lx];
    float u_m   = L[O_u  + e0 * PSZ + ly * PW + lx];
    float u_m_e = L[O_u  + e0 * PSZ + ly * PW + lx + 1];
    float v_m   = L[O_v  + e0 * PSZ + ly * PW + lx];
    float v_m_e = L[O_v  + e0 * PSZ + (ly + 1) * PW + lx];
    float w_m   = L[O_w  + e0 * PSZ + ly * PW + lx];

    // ================= main k loop =================
    for (int k = k0; k < k0 + KCH; ++k) {
        // consume zone: derive level k+1 (all staged data has landed)
        derive(k + 1, tid, A, L[O_TS + tid], L[O_WS + tid]);
        if (hasB) derive(k + 1, tid + 256, B, L[O_TS + tid + 256], L[O_WS + tid + 256]);
        __syncthreads();

        // issue async stage for future levels; lands during compute(k).
        // Skip on the last iteration (nothing consumes it).
        if (k < k0 + KCH - 1) stage(k);

        // ---- ring slot ids for compute(k) ----
        const int a5 = (k + 4) % 5, b5 = k % 5, c5 = (k + 1) % 5;
        const int aP = (k + 2) % 3, bP = k % 3, cP = (k + 1) % 3;
        const int m4 = k % 4, n4 = (k + 1) % 4;
        const int e = k & 1, f = 1 - e;
        const int eU = k % 3, fU = (k + 1) % 3;

        auto PHx = [&](int s, int rr, int cc) { return L[O_PH + s * ZP + rr * PW + cc]; };
        auto Px  = [&](int s, int rr, int cc) { return L[O_P  + s * PSZ + rr * PW + cc]; };
        auto Ox  = [&](int s, int rr, int cc) { return L[O_OM + s * PSZ + rr * PW + cc]; };
        auto MUx = [&](int s, int rr, int cc) { return L[O_MS + s * ZP + (rr + 1) * WW + cc + 1]; };
        auto THx = [&](int s, int rr, int cc) { return L[O_TH + s * PSZ + rr * PW + cc]; };
        auto URx = [&](int s, int rr, int cc) { return L[O_UR + s * ZP + rr * PW + cc]; };
        auto VRx = [&](int s, int rr, int cc) { return L[O_VR + s * ZP + rr * PW + cc]; };
        auto ux  = [&](int s, int rr, int cc) { return L[O_u  + s * PSZ + rr * PW + cc]; };
        auto vx  = [&](int s, int rr, int cc) { return L[O_v  + s * PSZ + rr * PW + cc]; };
        auto wx  = [&](int s, int rr, int cc) { return L[O_w  + s * PSZ + rr * PW + cc]; };
        auto ALk = [&](int rr, int cc) {
            return -(PHx(b5, rr, cc) - PHx(a5, rr, cc)) * RDZ * frcp(MUx(m4, rr, cc));
        };

        // ---- R_U at staggered col cc (pure LDS; PW covers cc=lx+1 for edge threads) ----
        auto R_U_c = [&](int cc, float ukm) -> float {
            const float u0 = ux(e, ly, cc), um = ux(e, ly, cc - 1), up = ux(e, ly, cc + 1);
            const float Uc = URx(eU, ly, cc), Um = URx(eU, ly, cc - 1), Up = URx(eU, ly, cc + 1);
            float r = -0.25f * ((Uc + Up) * (u0 + up) - (Um + Uc) * (um + u0)) * RDX;
            const float VBj  = 0.5f * (VRx(eU, ly, cc - 1) + VRx(eU, ly, cc));
            const float VBj1 = 0.5f * (VRx(eU, ly + 1, cc - 1) + VRx(eU, ly + 1, cc));
            const float uS = ux(e, ly - 1, cc), uN = ux(e, ly + 1, cc);
            r -= (VBj1 * 0.5f * (u0 + uN) - VBj * 0.5f * (uS + u0)) * RDY;
            const float OBk  = 0.5f * (Ox(aP, ly, cc - 1) + Ox(aP, ly, cc));
            const float OBk1 = 0.5f * (Ox(bP, ly, cc - 1) + Ox(bP, ly, cc));
            const float ukp = ux(f, ly, cc);
            r -= (OBk1 * 0.5f * (u0 + ukp) - OBk * 0.5f * (ukm + u0)) * RDZ;
            const float mux_ = 0.5f * (MUx(m4, ly, cc - 1) + MUx(m4, ly, cc));
            const float alx  = 0.5f * (ALk(ly, cc - 1) + ALk(ly, cc));
            const float dpx  = (Px(bP, ly, cc) - Px(bP, ly, cc - 1)) * RDX;
            r -= mux_ * alx * dpx;
            const float pzk  = 0.25f * (Px(aP, ly, cc - 1) + Px(bP, ly, cc - 1)
                                      + Px(aP, ly, cc)     + Px(bP, ly, cc));
            const float pzk1 = 0.25f * (Px(bP, ly, cc - 1) + Px(cP, ly, cc - 1)
                                      + Px(bP, ly, cc)     + Px(cP, ly, cc));
            const float dpz = (pzk1 - pzk) * RDZ;
            const float pza = 0.5f * (PHx(a5, ly, cc - 1) + PHx(b5, ly, cc - 1));
            const float pzb = 0.5f * (PHx(a5, ly, cc)     + PHx(b5, ly, cc));
            r -= dpz * (pzb - pza) * RDX;
            return r;
        };

        // ---- R_V at staggered row rr ----
        auto R_V_c = [&](int rr, float vkm) -> float {
            const float v0 = vx(e, rr, lx), vm = vx(e, rr - 1, lx), vp = vx(e, rr + 1, lx);
            const float Vc = VRx(eU, rr, lx), Vm = VRx(eU, rr - 1, lx), Vp = VRx(eU, rr + 1, lx);
            float r = -0.25f * ((Vc + Vp) * (v0 + vp) - (Vm + Vc) * (vm + v0)) * RDY;
            const float UBi  = 0.5f * (URx(eU, rr - 1, lx)     + URx(eU, rr, lx));
            const float UBi1 = 0.5f * (URx(eU, rr - 1, lx + 1) + URx(eU, rr, lx + 1));
            const float vW = vx(e, rr, lx - 1), vE = vx(e, rr, lx + 1);
            r -= (UBi1 * 0.5f * (v0 + vE) - UBi * 0.5f * (vW + v0)) * RDX;
            const float OBk  = 0.5f * (Ox(aP, rr - 1, lx) + Ox(aP, rr, lx));
            const float OBk1 = 0.5f * (Ox(bP, rr - 1, lx) + Ox(bP, rr, lx));
            const float vkp = vx(f, rr, lx);
            r -= (OBk1 * 0.5f * (v0 + vkp) - OBk * 0.5f * (vkm + v0)) * RDZ;
            const float muy = 0.5f * (MUx(m4, rr - 1, lx) + MUx(m4, rr, lx));
            const float aly = 0.5f * (ALk(rr - 1, lx) + ALk(rr, lx));
            const float dpy = (Px(bP, rr, lx) - Px(bP, rr - 1, lx)) * RDY;
            r -= muy * aly * dpy;
            const float pzk  = 0.25f * (Px(aP, rr - 1, lx) + Px(bP, rr - 1, lx)
                                      + Px(aP, rr, lx)     + Px(bP, rr, lx));
            const float pzk1 = 0.25f * (Px(bP, rr - 1, lx) + Px(cP, rr - 1, lx)
                                      + Px(bP, rr, lx)     + Px(cP, rr, lx));
            const float dpz = (pzk1 - pzk) * RDZ;
            const float pza = 0.5f * (PHx(a5, rr - 1, lx) + PHx(b5, rr - 1, lx));
            const float pzb = 0.5f * (PHx(a5, rr, lx)     + PHx(b5, rr, lx));
            r -= dpz * (pzb - pza) * RDY;
            return r;
        };

        // ===== R_Theta =====
        const float th0 = THx(e, ly, lx);
        float rT = -(URx(eU, ly, lx + 1) * 0.5f * (th0 + THx(e, ly, lx + 1))
                   - URx(eU, ly, lx)     * 0.5f * (THx(e, ly, lx - 1) + th0)) * RDX
                   -(VRx(eU, ly + 1, lx) * 0.5f * (th0 + THx(e, ly + 1, lx))
                   - VRx(eU, ly, lx)     * 0.5f * (THx(e, ly - 1, lx) + th0)) * RDY;
        const float th_p = THx(f, ly, lx);
        const float Hk  = Ox(aP, ly, lx) * 0.5f * (th_m + th0);
        const float Hk1 = Ox(bP, ly, lx) * 0.5f * (th0 + th_p);
        rT -= (Hk1 - Hk) * RDZ;

        // ===== R_Mu =====
        const float rM = -(URx(eU, ly, lx + 1) - URx(eU, ly, lx)) * RDX
                         -(VRx(eU, ly + 1, lx) - VRx(eU, ly, lx)) * RDY
                         -(Ox(bP, ly, lx) - Ox(aP, ly, lx)) * RDZ;

        // ===== stores (center) =====
        const int idc = (k * NY + j) * NX + i;
        To[idc] = T0[idc] + c * rT;
        Mo[idc] = M0[idc] + c * rM;
        const int idu = (k * NY + j) * NXU + i;
        Uo[idu] = U0[idu] + c * R_U_c(lx, u_m);
        const int idv = (k * (NY + 1) + j) * NX + i;
        Vo[idv] = V0[idv] + c * R_V_c(ly, v_m);

        // ===== R_W / R_Phi at half level k (k < NZ-1) =====
        if (k < NZ - 1) {
            const float w0 = wx(e, ly, lx);
            const float Uzi  = 0.5f * (URx(eU, ly, lx)     + URx(fU, ly, lx));
            const float Uzi1 = 0.5f * (URx(eU, ly, lx + 1) + URx(fU, ly, lx + 1));
            const float wW = wx(e, ly, lx - 1), wE = wx(e, ly, lx + 1);
            float rW = -(Uzi1 * 0.5f * (w0 + wE) - Uzi * 0.5f * (wW + w0)) * RDX;
            const float Vzj  = 0.5f * (VRx(eU, ly, lx)     + VRx(fU, ly, lx));
            const float Vzj1 = 0.5f * (VRx(eU, ly + 1, lx) + VRx(fU, ly + 1, lx));
            const float wS = wx(e, ly - 1, lx), wN = wx(e, ly + 1, lx);
            rW -= (Vzj1 * 0.5f * (w0 + wN) - Vzj * 0.5f * (wS + w0)) * RDY;
            const float OZk  = 0.5f * (Ox(aP, ly, lx) + Ox(bP, ly, lx));
            const float OZk1 = 0.5f * (Ox(bP, ly, lx) + Ox(cP, ly, lx));
            const float wkp = wx(f, ly, lx);
            rW -= (OZk1 * 0.5f * (w0 + wkp) - OZk * 0.5f * (w_m + w0)) * RDZ;
            const float muz = 0.5f * (MUx(m4, ly, lx) + MUx(n4, ly, lx));
            rW += G * ((Px(cP, ly, lx) - Px(bP, ly, lx)) * RDZ - muz);

            const float ubz = 0.25f * (ux(e, ly, lx) + ux(e, ly, lx + 1)
                                     + ux(f, ly, lx) + ux(f, ly, lx + 1));
            const float dfx = (PHx(b5, ly, lx + 1) - PHx(b5, ly, lx - 1)) * (0.5f * RDX);
            const float vbz = 0.25f * (vx(e, ly, lx) + vx(e, ly + 1, lx)
                                     + vx(f, ly, lx) + vx(f, ly + 1, lx));
            const float dfy = (PHx(b5, ly + 1, lx) - PHx(b5, ly - 1, lx)) * (0.5f * RDY);
            const float rmuz = frcp(muz);
            const float om   = Ox(bP, ly, lx) * rmuz;
            const float dfz  = (PHx(c5, ly, lx) - PHx(a5, ly, lx)) * (0.5f * RDZ);
            const float rP = -ubz * dfx - vbz * dfy - om * dfz + G * w0;

            Wo[idc] = W0[idc] + c * rW;
            Po[idc] = P0[idc] + c * rP;
        }

        // ===== extra staggered col II=NX / row JJ=NY (in-LDS, PW/PH cover them) =====
        if (i == NX - 1) {
            Uo[idu + 1] = U0[idu + 1] + c * R_U_c(lx + 1, u_m_e);
        }
        if (j == NY - 1) {
            const int idv2 = (k * (NY + 1) + NY) * NX + i;
            Vo[idv2] = V0[idv2] + c * R_V_c(ly + 1, v_m_e);
        }

        // ===== capture k-1 carries for next level =====
        th_m  = th0;
        u_m   = ux(e, ly, lx);
        u_m_e = ux(e, ly, lx + 1);
        v_m   = vx(e, ly, lx);
        v_m_e = vx(e, ly + 1, lx);
        w_m   = wx(e, ly, lx);

        __syncthreads();   // drains staged gll loads; next derive may read them
    }
}

} // anonymous namespace

extern "C" void kernel_launch(void* const* d_in, const int* in_sizes, int n_in,
                              void* d_out, int out_size, void* d_ws, size_t ws_size,
                              hipStream_t stream)
{
    (void)in_sizes; (void)n_in; (void)out_size; (void)ws_size;

    const float* U0   = (const float*)d_in[0];
    const float* V0   = (const float*)d_in[1];
    const float* W0   = (const float*)d_in[2];
    const float* T0   = (const float*)d_in[3];
    const float* M0   = (const float*)d_in[4];
    const float* P0   = (const float*)d_in[5];
    const float* Phit = (const float*)d_in[6];
    const float* Phis = (const float*)d_in[7];
    const float* Pt   = (const float*)d_in[8];
    const float* Psrf = (const float*)d_in[9];
    const int*   dtp  = (const int*)d_in[10];

    float* out = (float*)d_out;
    float* ws  = (float*)d_ws;

    float* outU = out;
    float* outV = outU + SZ_U;
    float* outW = outV + SZ_V;
    float* outT = outW + SZ_W;
    float* outM = outT + SZ_T;
    float* outP = outM + SZ_M;

    float* wsU = ws;
    float* wsV = wsU + SZ_U;
    float* wsW = wsV + SZ_V;
    float* wsT = wsW + SZ_W;
    float* wsM = wsT + SZ_T;
    float* wsP = wsM + SZ_M;

    const dim3 blk(TX, TY, 1);
    const dim3 grd(GX, GY, KSPLIT);

    const float coefs[3] = {1.0f / 3.0f, 0.5f, 1.0f};

    // stage ping-pong: d_in -> d_out -> ws -> d_out
    const float* sU[3] = {U0, outU, wsU};
    const float* sV[3] = {V0, outV, wsV};
    const float* sW[3] = {W0, outW, wsW};
    const float* sT[3] = {T0, outT, wsT};
    const float* sM[3] = {M0, outM, wsM};
    const float* sP_[3] = {P0, outP, wsP};
    float* oU[3] = {outU, wsU, outU};
    float* oV[3] = {outV, wsV, outV};
    float* oW[3] = {outW, wsW, outW};
    float* oT[3] = {outT, wsT, outT};
    float* oM[3] = {outM, wsM, outM};
    float* oP[3] = {outP, wsP, outP};

    for (int s = 0; s < 3; ++s) {
        rhs_tile<<<grd, blk, 0, stream>>>(
            sU[s], sV[s], sW[s], sT[s], sM[s], sP_[s],
            Phit, Phis, Pt, Psrf,
            U0, V0, W0, T0, M0, P0,
            oU[s], oV[s], oW[s], oT[s], oM[s], oP[s],
            dtp, coefs[s]);
    }
}

// Round 16
// 533.640 us; speedup vs baseline: 2.8062x; 1.0101x over previous
//
#include <hip/hip_runtime.h>

namespace {

constexpr int NX = 384, NY = 384, NZ = 48;
constexpr int NXU = NX + 1;
constexpr int PLN = NX * NY;
constexpr float RDX = 1.0f / 1000.0f;
constexpr float RDY = 1.0f / 1000.0f;
constexpr float RDZ = 49.0f;              // 1/DZ, DZ = 1/(NZ+1)
constexpr float PREF = 100000.0f, G = 9.81f;
constexpr float K_RP = 287.0f / PREF;

constexpr int SZ_U = NZ * NY * NXU;
constexpr int SZ_V = NZ * (NY + 1) * NX;
constexpr int SZ_W = (NZ - 1) * PLN;
constexpr int SZ_T = NZ * PLN;
constexpr int SZ_M = NZ * PLN;
constexpr int SZ_P = (NZ - 1) * PLN;

// tile geometry (32x8: 2 rows/wave at stride 35 -> 2-way LDS banking = free)
constexpr int TX = 32, TY = 8;            // 256 threads
constexpr int PW = TX + 3;                // 35 (cols i0-1 .. i0+33, incl. stagger col)
constexpr int PH = TY + 3;                // 11
constexpr int PSZ = PW * PH;              // 385
constexpr int WW = PW + 1;                // 36 wide-Ms plane (extra left col/top row)
constexpr int WH = PH + 1;                // 12
constexpr int WSZ = WW * WH;              // 432
constexpr int ZP = 448;                   // padded gll plane (multiple of 64)
constexpr int KCH = 12, KSPLIT = 4;

// grid / swizzle constants
constexpr int GX = NX / TX;               // 12
constexpr int GY = NY / TY;               // 48
constexpr int NWG = GX * GY * KSPLIT;     // 2304 (divisible by 8)
constexpr int CPX = NWG / 8;              // 288 blocks per XCD chunk

// LDS float offsets
constexpr int O_PH = 0;                   // 5 x ZP  direct: PHIP(m+1) at slot m%5
constexpr int O_MS = O_PH + 5 * ZP;       // 4 x ZP  direct: Ms wide, slot l%4
constexpr int O_UR = O_MS + 4 * ZP;       // 3 x ZP  direct: Us, slot l%3
constexpr int O_VR = O_UR + 3 * ZP;       // 3 x ZP  direct: Vs, slot l%3
constexpr int O_TS = O_VR + 3 * ZP;       // 1 x ZP  zone: Ts
constexpr int O_WS = O_TS + ZP;           // 1 x ZP  zone: Ws
constexpr int O_P  = O_WS + ZP;           // 3 x PSZ derived p-pad(l+1) at slot l%3
constexpr int O_OM = O_P  + 3 * PSZ;      // 3 x PSZ derived Omega(half l) at slot l%3
constexpr int O_TH = O_OM + 3 * PSZ;      // 2 x PSZ
constexpr int O_u  = O_TH + 2 * PSZ;      // 2 x PSZ
constexpr int O_v  = O_u  + 2 * PSZ;      // 2 x PSZ
constexpr int O_w  = O_v  + 2 * PSZ;      // 2 x PSZ
constexpr int LTOT = O_w + 2 * PSZ;       // 13,006 floats = 52,024 B -> 3 blocks/CU

struct PIdx { int pix, uo, vo, wc, oxa, oxb, oya, oyb; };

__device__ __forceinline__ float frcp(float x) { return __builtin_amdgcn_rcpf(x); }
__device__ __forceinline__ float pow14(float x) {
    return __builtin_amdgcn_exp2f(1.4f * __builtin_amdgcn_logf(x));
}
__device__ __forceinline__ void gll4(const float* src, float* ldsWaveBase) {
    __builtin_amdgcn_global_load_lds(
        (const __attribute__((address_space(1))) void*)src,
        (__attribute__((address_space(3))) void*)ldsWaveBase, 4, 0, 0);
}
__device__ __forceinline__ int imin(int a, int b) { return a < b ? a : b; }
__device__ __forceinline__ int imax(int a, int b) { return a > b ? a : b; }

__global__ __launch_bounds__(256, 3)
void rhs_tile(
    const float* __restrict__ Us, const float* __restrict__ Vs, const float* __restrict__ Ws,
    const float* __restrict__ Ts, const float* __restrict__ Ms, const float* __restrict__ Ps,
    const float* __restrict__ Phit, const float* __restrict__ Phis,
    const float* __restrict__ Pt,   const float* __restrict__ Psrf,
    const float* __restrict__ U0, const float* __restrict__ V0, const float* __restrict__ W0,
    const float* __restrict__ T0, const float* __restrict__ M0, const float* __restrict__ P0,
    float* __restrict__ Uo, float* __restrict__ Vo, float* __restrict__ Wo,
    float* __restrict__ To, float* __restrict__ Mo, float* __restrict__ Po,
    const int* __restrict__ dtp, float coef)
{
    __shared__ float L[LTOT];

    const int tx = threadIdx.x, ty = threadIdx.y;
    const int tid = ty * TX + tx;

    // ---- XCD-aware bijective block swizzle (each XCD gets a contiguous chunk) ----
    const int flat = blockIdx.x + GX * (blockIdx.y + GY * blockIdx.z);
    const int nf   = (flat & 7) * CPX + (flat >> 3);
    const int bx   = nf % GX;
    const int by   = (nf / GX) % GY;
    const int bz   = nf / (GX * GY);
    const int i0 = bx * TX;
    const int j0 = by * TY;
    const int k0 = bz * KCH;

    const int i = i0 + tx, j = j0 + ty;
    const float c = coef * (float)(*dtp);
    const int ly = ty + 1, lx = tx + 1;
    const int wb = tid & ~63;               // wave-uniform LDS base offset
    const bool w2 = (tid < 192);            // wave-uniform: waves 0..2 stage B-span
    const bool hasB = (tid + 256 < PSZ);    // B plane point exists
    const bool hasW = (tid + 256 < WSZ);

    // ---- per-point index sets (seam-corrected wide-mu offsets) ----
    auto mkpt = [&](int idx, PIdx& q) {
        const int r = idx / PW, cc = idx - r * PW;
        int gj = j0 - 1 + r;  if (gj < 0) gj += NY; else if (gj >= NY) gj -= NY;
        int gi = i0 - 1 + cc; if (gi < 0) gi += NX; else if (gi >= NX) gi -= NX;
        int gII = i0 - 1 + cc; if (gII < 0) gII += NX + 1; else if (gII > NX) gII -= NX + 1;
        int gJJ = j0 - 1 + r;  if (gJJ < 0) gJJ += NY + 1; else if (gJJ > NY) gJJ -= NY + 1;
        q.pix = gj * NX + gi;
        q.uo  = gj * NXU + gII;
        q.vo  = gJJ * NX + gi;
        q.wc  = (r + 1) * WW + (cc + 1);
        q.oxa = q.wc - 1; q.oxb = q.wc;
        if (i0 == 0 && cc == 0) { q.oxa = q.wc; q.oxb = q.wc + 1; }   // gII==NX via left wrap
        q.oya = q.wc - WW; q.oyb = q.wc;
        if (j0 == 0 && r == 0)  { q.oya = q.wc; q.oyb = q.wc + WW; }  // gJJ==NY via top wrap
    };
    auto mkwide = [&](int idxw) -> int {
        const int r = idxw / WW, cc = idxw - r * WW;
        int gj = j0 - 2 + r;  if (gj < 0) gj += NY; else if (gj >= NY) gj -= NY;
        int gi = i0 - 2 + cc; if (gi < 0) gi += NX; else if (gi >= NX) gi -= NX;
        return gj * NX + gi;
    };
    PIdx A, B;
    mkpt(tid, A);
    mkpt(imin(tid + 256, PSZ - 1), B);
    const int pwA = mkwide(tid);
    const int pwB = mkwide(imin(tid + 256, WSZ - 1));

    // ---- async stage for iteration k: Φ[k+3], Ms[k+3], U/V/Ts/Ws[k+2] ----
    auto stage = [&](int k) {
        {   // PHIP(m+1), m = k+3 -> slot (k+3)%5
            const int m = k + 3;
            const float* sA = (m >= NZ - 1) ? &Phis[A.pix] : &Ps[m * PLN + A.pix];
            gll4(sA, &L[O_PH + (m % 5) * ZP + wb]);
            if (w2) {
                const float* sB = (m >= NZ - 1) ? &Phis[B.pix] : &Ps[m * PLN + B.pix];
                gll4(sB, &L[O_PH + (m % 5) * ZP + wb + 256]);
            }
        }
        {   // Ms wide, level k+3
            const int lm = imin(k + 3, NZ - 1);
            gll4(&Ms[lm * PLN + pwA], &L[O_MS + ((k + 3) % 4) * ZP + wb]);
            if (w2) gll4(&Ms[lm * PLN + pwB], &L[O_MS + ((k + 3) % 4) * ZP + wb + 256]);
        }
        {   // U, V, Ts level k+2 ; Ws level k+2 (clamped)
            const int lc = imin(k + 2, NZ - 1);
            gll4(&Us[lc * NY * NXU + A.uo], &L[O_UR + ((k + 2) % 3) * ZP + wb]);
            if (w2) gll4(&Us[lc * NY * NXU + B.uo], &L[O_UR + ((k + 2) % 3) * ZP + wb + 256]);
            gll4(&Vs[lc * (NY + 1) * NX + A.vo], &L[O_VR + ((k + 2) % 3) * ZP + wb]);
            if (w2) gll4(&Vs[lc * (NY + 1) * NX + B.vo], &L[O_VR + ((k + 2) % 3) * ZP + wb + 256]);
            gll4(&Ts[lc * PLN + A.pix], &L[O_TS + wb]);
            if (w2) gll4(&Ts[lc * PLN + B.pix], &L[O_TS + wb + 256]);
            const int lw = imin(k + 2, NZ - 2);
            gll4(&Ws[lw * PLN + A.pix], &L[O_WS + wb]);
            if (w2) gll4(&Ws[lw * PLN + B.pix], &L[O_WS + wb + 256]);
        }
    };

    // ---- derive level l into derived rings ----
    auto derive = [&](int l, int idx, const PIdx& q, float tsv, float wsv) {
        const int s3 = ((l % 3) + 3) % 3, s2 = l & 1;
        float pv, th = 0.f, uv = 0.f, vv = 0.f, wv = 0.f, om = 0.f;
        if (l >= 0 && l < NZ) {
            const int m4 = l % 4, m5 = l % 5, p5 = ((l - 1) % 5 + 5) % 5;
            const float mu  = L[O_MS + m4 * ZP + q.wc];
            const float phv = L[O_PH + m5 * ZP + idx];
            const float phm = L[O_PH + p5 * ZP + idx];
            const float rmu = frcp(mu);
            const float al  = -(phv - phm) * RDZ * rmu;
            th = tsv * rmu;
            pv = PREF * pow14(K_RP * th * frcp(al));
            uv = L[O_UR + (l % 3) * ZP + idx]
                 * frcp(0.5f * (L[O_MS + m4 * ZP + q.oxa] + L[O_MS + m4 * ZP + q.oxb]));
            vv = L[O_VR + (l % 3) * ZP + idx]
                 * frcp(0.5f * (L[O_MS + m4 * ZP + q.oya] + L[O_MS + m4 * ZP + q.oyb]));
            if (l < NZ - 1) {
                const float mu1 = L[O_MS + ((l + 1) % 4) * ZP + q.wc];
                const float ph1 = L[O_PH + ((l + 1) % 5) * ZP + idx];
                const float al1 = -(ph1 - phv) * RDZ * frcp(mu1);
                const float mz  = 0.5f * (mu + mu1);
                wv = wsv * frcp(mz);
                om = -wsv * G * frcp(0.5f * (al + al1) * mz);
            }
        } else {
            pv = (l < 0) ? Pt[q.pix] : Psrf[q.pix];
        }
        L[O_P  + s3 * PSZ + idx] = pv;
        L[O_OM + s3 * PSZ + idx] = om;
        L[O_TH + s2 * PSZ + idx] = th;
        L[O_u  + s2 * PSZ + idx] = uv;
        L[O_v  + s2 * PSZ + idx] = vv;
        L[O_w  + s2 * PSZ + idx] = wv;
    };

    // ================= prologue: direct ring fills =================
    {
        for (int m = k0 - 2; m <= k0 + 2; ++m) {
            const float v = (m >= NZ - 1) ? Phis[A.pix]
                          : ((m < 0) ? Phit[A.pix] : Ps[m * PLN + A.pix]);
            L[O_PH + ((m % 5 + 5) % 5) * ZP + tid] = v;
        }
        for (int l = k0 - 1; l <= k0 + 2; ++l) {
            const int lc = imin(imax(l, 0), NZ - 1);
            L[O_MS + ((l % 4 + 4) % 4) * ZP + tid] = Ms[lc * PLN + pwA];
        }
        for (int l = k0 - 1; l <= k0 + 1; ++l) {
            const int lc = imin(imax(l, 0), NZ - 1);
            L[O_UR + ((l % 3 + 3) % 3) * ZP + tid] = Us[lc * NY * NXU + A.uo];
            L[O_VR + ((l % 3 + 3) % 3) * ZP + tid] = Vs[lc * (NY + 1) * NX + A.vo];
        }
        if (hasB) {
            const int idx = tid + 256;
            for (int m = k0 - 2; m <= k0 + 2; ++m) {
                const float v = (m >= NZ - 1) ? Phis[B.pix]
                              : ((m < 0) ? Phit[B.pix] : Ps[m * PLN + B.pix]);
                L[O_PH + ((m % 5 + 5) % 5) * ZP + idx] = v;
            }
            for (int l = k0 - 1; l <= k0 + 1; ++l) {
                const int lc = imin(imax(l, 0), NZ - 1);
                L[O_UR + ((l % 3 + 3) % 3) * ZP + idx] = Us[lc * NY * NXU + B.uo];
                L[O_VR + ((l % 3 + 3) % 3) * ZP + idx] = Vs[lc * (NY + 1) * NX + B.vo];
            }
        }
        if (hasW) {
            const int idx = tid + 256;
            for (int l = k0 - 1; l <= k0 + 2; ++l) {
                const int lc = imin(imax(l, 0), NZ - 1);
                L[O_MS + ((l % 4 + 4) % 4) * ZP + idx] = Ms[lc * PLN + pwB];
            }
        }
    }
    __syncthreads();

    // prologue derives for levels k0-1, k0 (Ts/Ws direct from global)
    {
        int lc = imin(imax(k0 - 1, 0), NZ - 1), lw = imin(imax(k0 - 1, 0), NZ - 2);
        derive(k0 - 1, tid, A, Ts[lc * PLN + A.pix], Ws[lw * PLN + A.pix]);
        if (hasB) derive(k0 - 1, tid + 256, B, Ts[lc * PLN + B.pix], Ws[lw * PLN + B.pix]);
        lc = imin(k0, NZ - 1); lw = imin(k0, NZ - 2);
        derive(k0, tid, A, Ts[lc * PLN + A.pix], Ws[lw * PLN + A.pix]);
        if (hasB) derive(k0, tid + 256, B, Ts[lc * PLN + B.pix], Ws[lw * PLN + B.pix]);
    }
    {   // stage Ts/Ws zone for level k0+1
        const int lc = imin(k0 + 1, NZ - 1), lw = imin(k0 + 1, NZ - 2);
        gll4(&Ts[lc * PLN + A.pix], &L[O_TS + wb]);
        if (w2) gll4(&Ts[lc * PLN + B.pix], &L[O_TS + wb + 256]);
        gll4(&Ws[lw * PLN + A.pix], &L[O_WS + wb]);
        if (w2) gll4(&Ws[lw * PLN + B.pix], &L[O_WS + wb + 256]);
    }
    __syncthreads();   // drains gll; orders prologue derived-ring writes

    // carried k-1 center registers (level k0-1)
    const int e0 = (k0 - 1) & 1;
    float th_m  = L[O_TH + e0 * PSZ + ly * PW + lx];
    float u_m   = L[O_u  + e0 * PSZ + ly * PW + lx];
    float u_m_e = L[O_u  + e0 * PSZ + ly * PW + lx + 1];
    float v_m   = L[O_v  + e0 * PSZ + ly * PW + lx];
    float v_m_e = L[O_v  + e0 * PSZ + (ly + 1) * PW + lx];
    float w_m   = L[O_w  + e0 * PSZ + ly * PW + lx];

    // ================= main k loop =================
    for (int k = k0; k < k0 + KCH; ++k) {
        // consume zone: derive level k+1 (all staged data has landed)
        derive(k + 1, tid, A, L[O_TS + tid], L[O_WS + tid]);
        if (hasB) derive(k + 1, tid + 256, B, L[O_TS + tid + 256], L[O_WS + tid + 256]);
        __syncthreads();

        // issue async stage for future levels; lands during compute(k).
        // Skip on the last iteration (nothing consumes it).
        if (k < k0 + KCH - 1) stage(k);

        // T5: boost priority through the compute phase — co-resident blocks on
        // this CU are at different phases (derive/stage), so the scheduler can
        // favor our VALU/LDS-bound compute waves while their loads are in flight.
        __builtin_amdgcn_s_setprio(1);

        // ---- ring slot ids for compute(k) ----
        const int a5 = (k + 4) % 5, b5 = k % 5, c5 = (k + 1) % 5;
        const int aP = (k + 2) % 3, bP = k % 3, cP = (k + 1) % 3;
        const int m4 = k % 4, n4 = (k + 1) % 4;
        const int e = k & 1, f = 1 - e;
        const int eU = k % 3, fU = (k + 1) % 3;

        auto PHx = [&](int s, int rr, int cc) { return L[O_PH + s * ZP + rr * PW + cc]; };
        auto Px  = [&](int s, int rr, int cc) { return L[O_P  + s * PSZ + rr * PW + cc]; };
        auto Ox  = [&](int s, int rr, int cc) { return L[O_OM + s * PSZ + rr * PW + cc]; };
        auto MUx = [&](int s, int rr, int cc) { return L[O_MS + s * ZP + (rr + 1) * WW + cc + 1]; };
        auto THx = [&](int s, int rr, int cc) { return L[O_TH + s * PSZ + rr * PW + cc]; };
        auto URx = [&](int s, int rr, int cc) { return L[O_UR + s * ZP + rr * PW + cc]; };
        auto VRx = [&](int s, int rr, int cc) { return L[O_VR + s * ZP + rr * PW + cc]; };
        auto ux  = [&](int s, int rr, int cc) { return L[O_u  + s * PSZ + rr * PW + cc]; };
        auto vx  = [&](int s, int rr, int cc) { return L[O_v  + s * PSZ + rr * PW + cc]; };
        auto wx  = [&](int s, int rr, int cc) { return L[O_w  + s * PSZ + rr * PW + cc]; };
        auto ALk = [&](int rr, int cc) {
            return -(PHx(b5, rr, cc) - PHx(a5, rr, cc)) * RDZ * frcp(MUx(m4, rr, cc));
        };

        // ---- R_U at staggered col cc (pure LDS; PW covers cc=lx+1 for edge threads) ----
        auto R_U_c = [&](int cc, float ukm) -> float {
            const float u0 = ux(e, ly, cc), um = ux(e, ly, cc - 1), up = ux(e, ly, cc + 1);
            const float Uc = URx(eU, ly, cc), Um = URx(eU, ly, cc - 1), Up = URx(eU, ly, cc + 1);
            float r = -0.25f * ((Uc + Up) * (u0 + up) - (Um + Uc) * (um + u0)) * RDX;
            const float VBj  = 0.5f * (VRx(eU, ly, cc - 1) + VRx(eU, ly, cc));
            const float VBj1 = 0.5f * (VRx(eU, ly + 1, cc - 1) + VRx(eU, ly + 1, cc));
            const float uS = ux(e, ly - 1, cc), uN = ux(e, ly + 1, cc);
            r -= (VBj1 * 0.5f * (u0 + uN) - VBj * 0.5f * (uS + u0)) * RDY;
            const float OBk  = 0.5f * (Ox(aP, ly, cc - 1) + Ox(aP, ly, cc));
            const float OBk1 = 0.5f * (Ox(bP, ly, cc - 1) + Ox(bP, ly, cc));
            const float ukp = ux(f, ly, cc);
            r -= (OBk1 * 0.5f * (u0 + ukp) - OBk * 0.5f * (ukm + u0)) * RDZ;
            const float mux_ = 0.5f * (MUx(m4, ly, cc - 1) + MUx(m4, ly, cc));
            const float alx  = 0.5f * (ALk(ly, cc - 1) + ALk(ly, cc));
            const float dpx  = (Px(bP, ly, cc) - Px(bP, ly, cc - 1)) * RDX;
            r -= mux_ * alx * dpx;
            const float pzk  = 0.25f * (Px(aP, ly, cc - 1) + Px(bP, ly, cc - 1)
                                      + Px(aP, ly, cc)     + Px(bP, ly, cc));
            const float pzk1 = 0.25f * (Px(bP, ly, cc - 1) + Px(cP, ly, cc - 1)
                                      + Px(bP, ly, cc)     + Px(cP, ly, cc));
            const float dpz = (pzk1 - pzk) * RDZ;
            const float pza = 0.5f * (PHx(a5, ly, cc - 1) + PHx(b5, ly, cc - 1));
            const float pzb = 0.5f * (PHx(a5, ly, cc)     + PHx(b5, ly, cc));
            r -= dpz * (pzb - pza) * RDX;
            return r;
        };

        // ---- R_V at staggered row rr ----
        auto R_V_c = [&](int rr, float vkm) -> float {
            const float v0 = vx(e, rr, lx), vm = vx(e, rr - 1, lx), vp = vx(e, rr + 1, lx);
            const float Vc = VRx(eU, rr, lx), Vm = VRx(eU, rr - 1, lx), Vp = VRx(eU, rr + 1, lx);
            float r = -0.25f * ((Vc + Vp) * (v0 + vp) - (Vm + Vc) * (vm + v0)) * RDY;
            const float UBi  = 0.5f * (URx(eU, rr - 1, lx)     + URx(eU, rr, lx));
            const float UBi1 = 0.5f * (URx(eU, rr - 1, lx + 1) + URx(eU, rr, lx + 1));
            const float vW = vx(e, rr, lx - 1), vE = vx(e, rr, lx + 1);
            r -= (UBi1 * 0.5f * (v0 + vE) - UBi * 0.5f * (vW + v0)) * RDX;
            const float OBk  = 0.5f * (Ox(aP, rr - 1, lx) + Ox(aP, rr, lx));
            const float OBk1 = 0.5f * (Ox(bP, rr - 1, lx) + Ox(bP, rr, lx));
            const float vkp = vx(f, rr, lx);
            r -= (OBk1 * 0.5f * (v0 + vkp) - OBk * 0.5f * (vkm + v0)) * RDZ;
            const float muy = 0.5f * (MUx(m4, rr - 1, lx) + MUx(m4, rr, lx));
            const float aly = 0.5f * (ALk(rr - 1, lx) + ALk(rr, lx));
            const float dpy = (Px(bP, rr, lx) - Px(bP, rr - 1, lx)) * RDY;
            r -= muy * aly * dpy;
            const float pzk  = 0.25f * (Px(aP, rr - 1, lx) + Px(bP, rr - 1, lx)
                                      + Px(aP, rr, lx)     + Px(bP, rr, lx));
            const float pzk1 = 0.25f * (Px(bP, rr - 1, lx) + Px(cP, rr - 1, lx)
                                      + Px(bP, rr, lx)     + Px(cP, rr, lx));
            const float dpz = (pzk1 - pzk) * RDZ;
            const float pza = 0.5f * (PHx(a5, rr - 1, lx) + PHx(b5, rr - 1, lx));
            const float pzb = 0.5f * (PHx(a5, rr, lx)     + PHx(b5, rr, lx));
            r -= dpz * (pzb - pza) * RDY;
            return r;
        };

        // ===== R_Theta =====
        const float th0 = THx(e, ly, lx);
        float rT = -(URx(eU, ly, lx + 1) * 0.5f * (th0 + THx(e, ly, lx + 1))
                   - URx(eU, ly, lx)     * 0.5f * (THx(e, ly, lx - 1) + th0)) * RDX
                   -(VRx(eU, ly + 1, lx) * 0.5f * (th0 + THx(e, ly + 1, lx))
                   - VRx(eU, ly, lx)     * 0.5f * (THx(e, ly - 1, lx) + th0)) * RDY;
        const float th_p = THx(f, ly, lx);
        const float Hk  = Ox(aP, ly, lx) * 0.5f * (th_m + th0);
        const float Hk1 = Ox(bP, ly, lx) * 0.5f * (th0 + th_p);
        rT -= (Hk1 - Hk) * RDZ;

        // ===== R_Mu =====
        const float rM = -(URx(eU, ly, lx + 1) - URx(eU, ly, lx)) * RDX
                         -(VRx(eU, ly + 1, lx) - VRx(eU, ly, lx)) * RDY
                         -(Ox(bP, ly, lx) - Ox(aP, ly, lx)) * RDZ;

        // ===== stores (center) =====
        const int idc = (k * NY + j) * NX + i;
        To[idc] = T0[idc] + c * rT;
        Mo[idc] = M0[idc] + c * rM;
        const int idu = (k * NY + j) * NXU + i;
        Uo[idu] = U0[idu] + c * R_U_c(lx, u_m);
        const int idv = (k * (NY + 1) + j) * NX + i;
        Vo[idv] = V0[idv] + c * R_V_c(ly, v_m);

        // ===== R_W / R_Phi at half level k (k < NZ-1) =====
        if (k < NZ - 1) {
            const float w0 = wx(e, ly, lx);
            const float Uzi  = 0.5f * (URx(eU, ly, lx)     + URx(fU, ly, lx));
            const float Uzi1 = 0.5f * (URx(eU, ly, lx + 1) + URx(fU, ly, lx + 1));
            const float wW = wx(e, ly, lx - 1), wE = wx(e, ly, lx + 1);
            float rW = -(Uzi1 * 0.5f * (w0 + wE) - Uzi * 0.5f * (wW + w0)) * RDX;
            const float Vzj  = 0.5f * (VRx(eU, ly, lx)     + VRx(fU, ly, lx));
            const float Vzj1 = 0.5f * (VRx(eU, ly + 1, lx) + VRx(fU, ly + 1, lx));
            const float wS = wx(e, ly - 1, lx), wN = wx(e, ly + 1, lx);
            rW -= (Vzj1 * 0.5f * (w0 + wN) - Vzj * 0.5f * (wS + w0)) * RDY;
            const float OZk  = 0.5f * (Ox(aP, ly, lx) + Ox(bP, ly, lx));
            const float OZk1 = 0.5f * (Ox(bP, ly, lx) + Ox(cP, ly, lx));
            const float wkp = wx(f, ly, lx);
            rW -= (OZk1 * 0.5f * (w0 + wkp) - OZk * 0.5f * (w_m + w0)) * RDZ;
            const float muz = 0.5f * (MUx(m4, ly, lx) + MUx(n4, ly, lx));
            rW += G * ((Px(cP, ly, lx) - Px(bP, ly, lx)) * RDZ - muz);

            const float ubz = 0.25f * (ux(e, ly, lx) + ux(e, ly, lx + 1)
                                     + ux(f, ly, lx) + ux(f, ly, lx + 1));
            const float dfx = (PHx(b5, ly, lx + 1) - PHx(b5, ly, lx - 1)) * (0.5f * RDX);
            const float vbz = 0.25f * (vx(e, ly, lx) + vx(e, ly + 1, lx)
                                     + vx(f, ly, lx) + vx(f, ly + 1, lx));
            const float dfy = (PHx(b5, ly + 1, lx) - PHx(b5, ly - 1, lx)) * (0.5f * RDY);
            const float rmuz = frcp(muz);
            const float om   = Ox(bP, ly, lx) * rmuz;
            const float dfz  = (PHx(c5, ly, lx) - PHx(a5, ly, lx)) * (0.5f * RDZ);
            const float rP = -ubz * dfx - vbz * dfy - om * dfz + G * w0;

            Wo[idc] = W0[idc] + c * rW;
            Po[idc] = P0[idc] + c * rP;
        }

        // ===== extra staggered col II=NX / row JJ=NY (in-LDS, PW/PH cover them) =====
        if (i == NX - 1) {
            Uo[idu + 1] = U0[idu + 1] + c * R_U_c(lx + 1, u_m_e);
        }
        if (j == NY - 1) {
            const int idv2 = (k * (NY + 1) + NY) * NX + i;
            Vo[idv2] = V0[idv2] + c * R_V_c(ly + 1, v_m_e);
        }

        // ===== capture k-1 carries for next level =====
        th_m  = th0;
        u_m   = ux(e, ly, lx);
        u_m_e = ux(e, ly, lx + 1);
        v_m   = vx(e, ly, lx);
        v_m_e = vx(e, ly + 1, lx);
        w_m   = wx(e, ly, lx);

        __builtin_amdgcn_s_setprio(0);
        __syncthreads();   // drains staged gll loads; next derive may read them
    }
}

} // anonymous namespace

extern "C" void kernel_launch(void* const* d_in, const int* in_sizes, int n_in,
                              void* d_out, int out_size, void* d_ws, size_t ws_size,
                              hipStream_t stream)
{
    (void)in_sizes; (void)n_in; (void)out_size; (void)ws_size;

    const float* U0   = (const float*)d_in[0];
    const float* V0   = (const float*)d_in[1];
    const float* W0   = (const float*)d_in[2];
    const float* T0   = (const float*)d_in[3];
    const float* M0   = (const float*)d_in[4];
    const float* P0   = (const float*)d_in[5];
    const float* Phit = (const float*)d_in[6];
    const float* Phis = (const float*)d_in[7];
    const float* Pt   = (const float*)d_in[8];
    const float* Psrf = (const float*)d_in[9];
    const int*   dtp  = (const int*)d_in[10];

    float* out = (float*)d_out;
    float* ws  = (float*)d_ws;

    float* outU = out;
    float* outV = outU + SZ_U;
    float* outW = outV + SZ_V;
    float* outT = outW + SZ_W;
    float* outM = outT + SZ_T;
    float* outP = outM + SZ_M;

    float* wsU = ws;
    float* wsV = wsU + SZ_U;
    float* wsW = wsV + SZ_V;
    float* wsT = wsW + SZ_W;
    float* wsM = wsT + SZ_T;
    float* wsP = wsM + SZ_M;

    const dim3 blk(TX, TY, 1);
    const dim3 grd(GX, GY, KSPLIT);

    const float coefs[3] = {1.0f / 3.0f, 0.5f, 1.0f};

    // stage ping-pong: d_in -> d_out -> ws -> d_out
    const float* sU[3] = {U0, outU, wsU};
    const float* sV[3] = {V0, outV, wsV};
    const float* sW[3] = {W0, outW, wsW};
    const float* sT[3] = {T0, outT, wsT};
    const float* sM[3] = {M0, outM, wsM};
    const float* sP_[3] = {P0, outP, wsP};
    float* oU[3] = {outU, wsU, outU};
    float* oV[3] = {outV, wsV, outV};
    float* oW[3] = {outW, wsW, outW};
    float* oT[3] = {outT, wsT, outT};
    float* oM[3] = {outM, wsM, outM};
    float* oP[3] = {outP, wsP, outP};

    for (int s = 0; s < 3; ++s) {
        rhs_tile<<<grd, blk, 0, stream>>>(
            sU[s], sV[s], sW[s], sT[s], sM[s], sP_[s],
            Phit, Phis, Pt, Psrf,
            U0, V0, W0, T0, M0, P0,
            oU[s], oV[s], oW[s], oT[s], oM[s], oP[s],
            dtp, coefs[s]);
    }
}